// Round 1
// baseline (771.545 us; speedup 1.0000x reference)
//
#include <hip/hip_runtime.h>
#include <hip/hip_bf16.h>

// Problem constants
#define PDIM 4096
#define BDIM 32
#define MDIM (PDIM*BDIM)   // 131072 rows of x
#define KDIM 512           // FEAT
#define NDIM 512           // ATTN
#define NH   8
#define HD   64

typedef __attribute__((ext_vector_type(4))) float f32x4;
typedef __attribute__((ext_vector_type(8))) short bf16x8;

__device__ __forceinline__ unsigned short f2bf(float f) {
  unsigned u = __float_as_uint(f);
  u += 0x7fffu + ((u >> 16) & 1u);
  return (unsigned short)(u >> 16);
}

// fast tanh via exp; abs error ~1e-7, arg clamped so no overflow
__device__ __forceinline__ float fast_tanh(float x) {
  x = fminf(fmaxf(x, -15.f), 15.f);
  float e = __expf(2.f * x);
  return __fdividef(e - 1.f, e + 1.f);
}

// ---------------- setup kernels (tiny) ----------------

// hid[b,a] = last_hidden[b] @ Ua + Ua_b
__global__ __launch_bounds__(512) void hid_k(
    const float* __restrict__ lh, const float* __restrict__ Ua,
    const float* __restrict__ Ua_b, float* __restrict__ hid) {
  int b = blockIdx.x, tid = threadIdx.x;
  __shared__ float ls[512];
  ls[tid] = lh[b*512 + tid];
  __syncthreads();
  float s = Ua_b[tid];
  #pragma unroll 8
  for (int k = 0; k < 512; ++k)
    s += ls[k] * Ua[(size_t)k*512 + tid];
  hid[b*512 + tid] = s;
}

// ubf[b,n] = (hid[b,h]@Ua2)[j] + Ua2_b[j] + (Wa_b[h]@Wa2)[j] + Wa2_b[j], n=h*64+j
__global__ __launch_bounds__(512) void ubf_k(
    const float* __restrict__ hid, const float* __restrict__ Ua2,
    const float* __restrict__ Ua2_b, const float* __restrict__ Wa_b,
    const float* __restrict__ Wa2, const float* __restrict__ Wa2_b,
    float* __restrict__ ubf) {
  int b = blockIdx.x, tid = threadIdx.x;
  __shared__ float hs[512];
  hs[tid] = hid[b*512 + tid];
  __syncthreads();
  int h = tid >> 6, j = tid & 63;
  float s = Ua2_b[j] + Wa2_b[j];
  #pragma unroll 4
  for (int k = 0; k < 64; ++k) {
    s += hs[h*64 + k] * Ua2[k*64 + j];
    s += Wa_b[h*64 + k] * Wa2[k*64 + j];
  }
  ubf[b*512 + tid] = s;
}

// WfT[n,k] = sum_kk Wa[k, h*64+kk] * Wa2[kk, j]   (bf16, N-major = B^T for GEMM)
__global__ __launch_bounds__(256) void wft_k(
    const float* __restrict__ Wa, const float* __restrict__ Wa2,
    unsigned short* __restrict__ WfT) {
  int n = blockIdx.x, tid = threadIdx.x;
  int h = n >> 6, j = n & 63;
  __shared__ float w2[64];
  if (tid < 64) w2[tid] = Wa2[tid*64 + j];
  __syncthreads();
  for (int k = tid; k < 512; k += 256) {
    float s = 0.f;
    #pragma unroll 8
    for (int kk = 0; kk < 64; ++kk)
      s += Wa[(size_t)k*512 + h*64 + kk] * w2[kk];
    WfT[(size_t)n*512 + k] = f2bf(s);
  }
}

// ---------------- main GEMM + score epilogue ----------------
// C[m,n] = x[m,:] @ Wf[:,n]; then score[m,h] = va_b + sum_j tanh(C+ubf)*va[j]
#define SA 72  // LDS row stride (64 + 8 pad bf16)

__global__ __launch_bounds__(256, 2) void gemm_score_k(
    const float* __restrict__ x, const unsigned short* __restrict__ WfT,
    const float* __restrict__ ubf, const float* __restrict__ va_w,
    const float* __restrict__ va_b, float* __restrict__ scores) {
  __shared__ __align__(16) unsigned short As[128*SA];
  __shared__ __align__(16) unsigned short Bs[128*SA];
  __shared__ float ubf_s[32*128];
  int tid = threadIdx.x;
  int bn = blockIdx.x, bm = blockIdx.y;   // bn fast in dispatch -> A-tile LLC reuse
  int m0 = bm*128, n0 = bn*128;
  // stage the 32x128 ubf slice for this column block
  #pragma unroll
  for (int t = 0; t < 16; ++t) {
    int idx = t*256 + tid;
    ubf_s[idx] = ubf[(idx >> 7)*512 + n0 + (idx & 127)];
  }
  int lane = tid & 63, w = tid >> 6;
  int quad = lane >> 4, l16 = lane & 15;
  int wr = w >> 1, wc = w & 1;
  f32x4 acc[4][4] = {};

  for (int k0 = 0; k0 < KDIM; k0 += 64) {
    __syncthreads();
    // stage A: 128 rows x 64 k, fp32 -> bf16
    #pragma unroll
    for (int t = 0; t < 8; ++t) {
      int idx = t*256 + tid;
      int r = idx >> 4, c4 = idx & 15;
      const float4 vv = *(const float4*)(x + (size_t)(m0 + r)*KDIM + k0 + c4*4);
      ushort4 o;
      o.x = f2bf(vv.x); o.y = f2bf(vv.y); o.z = f2bf(vv.z); o.w = f2bf(vv.w);
      *(ushort4*)(&As[r*SA + c4*4]) = o;
    }
    // stage B (already bf16, B^T layout: n-major, k-contiguous)
    #pragma unroll
    for (int t = 0; t < 4; ++t) {
      int idx = t*256 + tid;
      int r = idx >> 3, c8 = idx & 7;
      uint4 vv = *(const uint4*)(WfT + (size_t)(n0 + r)*KDIM + k0 + c8*8);
      *(uint4*)(&Bs[r*SA + c8*8]) = vv;
    }
    __syncthreads();
    #pragma unroll
    for (int kk = 0; kk < 64; kk += 32) {
      bf16x8 af[4], bfr[4];
      #pragma unroll
      for (int ti = 0; ti < 4; ++ti)
        af[ti] = *(const bf16x8*)(&As[(64*wr + 16*ti + l16)*SA + kk + quad*8]);
      #pragma unroll
      for (int tj = 0; tj < 4; ++tj)
        bfr[tj] = *(const bf16x8*)(&Bs[(64*wc + 16*tj + l16)*SA + kk + quad*8]);
      #pragma unroll
      for (int ti = 0; ti < 4; ++ti)
        #pragma unroll
        for (int tj = 0; tj < 4; ++tj)
          acc[ti][tj] = __builtin_amdgcn_mfma_f32_16x16x32_bf16(
              af[ti], bfr[tj], acc[ti][tj], 0, 0, 0);
    }
  }

  // epilogue: tanh, dot with va over this head's 64 cols, write score
  int head = bn*2 + wc;
  float va_r[4];
  #pragma unroll
  for (int tj = 0; tj < 4; ++tj) va_r[tj] = va_w[16*tj + l16];
  float vb = va_b[0];
  #pragma unroll
  for (int ti = 0; ti < 4; ++ti) {
    #pragma unroll
    for (int r = 0; r < 4; ++r) {
      int row_loc = 64*wr + 16*ti + 4*quad + r;   // C/D layout: row=quad*4+reg
      int b31 = row_loc & 31;                     // batch index = row % 32
      float s = 0.f;
      #pragma unroll
      for (int tj = 0; tj < 4; ++tj) {
        float xa = acc[ti][tj][r] + ubf_s[b31*128 + 64*wc + 16*tj + l16];
        s += fast_tanh(xa) * va_r[tj];
      }
      s += __shfl_xor(s, 1); s += __shfl_xor(s, 2);
      s += __shfl_xor(s, 4); s += __shfl_xor(s, 8);
      if (l16 == 0) scores[(size_t)(m0 + row_loc)*NH + head] = s + vb;
    }
  }
}

// ---------------- softmax over P per (b,h) ----------------
__global__ __launch_bounds__(256) void softmax_k(
    const float* __restrict__ sc, float* __restrict__ w) {
  int b = blockIdx.x >> 3, h = blockIdx.x & 7;
  int tid = threadIdx.x;
  float v[16];
  float mx = -1e30f;
  #pragma unroll
  for (int i = 0; i < 16; ++i) {
    int p = tid + i*256;
    v[i] = sc[(size_t)(p*32 + b)*NH + h];
    mx = fmaxf(mx, v[i]);
  }
  for (int m = 1; m < 64; m <<= 1) mx = fmaxf(mx, __shfl_xor(mx, m));
  __shared__ float redm[4], reds[4];
  int wid = tid >> 6, lane = tid & 63;
  if (lane == 0) redm[wid] = mx;
  __syncthreads();
  mx = fmaxf(fmaxf(redm[0], redm[1]), fmaxf(redm[2], redm[3]));
  float sum = 0.f;
  #pragma unroll
  for (int i = 0; i < 16; ++i) { v[i] = __expf(v[i] - mx); sum += v[i]; }
  for (int m = 1; m < 64; m <<= 1) sum += __shfl_xor(sum, m);
  if (lane == 0) reds[wid] = sum;
  __syncthreads();
  sum = reds[0] + reds[1] + reds[2] + reds[3];
  float inv = 1.f / sum;
  #pragma unroll
  for (int i = 0; i < 16; ++i) {
    int p = tid + i*256;
    w[(size_t)(p*32 + b)*NH + h] = v[i] * inv;
  }
}

// weight output = mean over heads
__global__ __launch_bounds__(256) void mean_k(
    const float* __restrict__ w, float* __restrict__ out) {
  int m = blockIdx.x*256 + threadIdx.x;
  const float4* p = (const float4*)(w + (size_t)m*NH);
  float4 a = p[0], c = p[1];
  out[BDIM*NDIM + m] = (a.x+a.y+a.z+a.w + c.x+c.y+c.z+c.w) * 0.125f;
}

// ---------------- context: cx[b,h,f] = sum_p w[p,b,h]*x[p,b,f] ----------------
__global__ __launch_bounds__(512) void ctx_partial_k(
    const float* __restrict__ x, const float* __restrict__ w,
    float* __restrict__ part) {
  int ch = blockIdx.x, b = blockIdx.y;
  int tid = threadIdx.x;
  __shared__ float wl[128*8];
  #pragma unroll
  for (int t = 0; t < 2; ++t) {
    int i = t*512 + tid;
    wl[i] = w[(size_t)(ch*128 + (i >> 3))*256 + b*8 + (i & 7)];
  }
  __syncthreads();
  float acc[8] = {0.f,0.f,0.f,0.f,0.f,0.f,0.f,0.f};
  #pragma unroll 4
  for (int pl = 0; pl < 128; ++pl) {
    float xv = x[(size_t)(ch*128 + pl)*16384 + b*512 + tid];
    #pragma unroll
    for (int h = 0; h < 8; ++h) acc[h] += xv * wl[pl*8 + h];
  }
  #pragma unroll
  for (int h = 0; h < 8; ++h)
    part[(size_t)((b*32 + ch)*8 + h)*512 + tid] = acc[h];
}

__global__ __launch_bounds__(256) void ctx_reduce_k(
    const float* __restrict__ part, float* __restrict__ cx) {
  int gid = blockIdx.x*256 + threadIdx.x;  // (b*8+h)*512+f
  int f = gid & 511;
  int bh = gid >> 9;
  int h = bh & 7, b = bh >> 3;
  float s = 0.f;
  #pragma unroll 8
  for (int c = 0; c < 32; ++c)
    s += part[(size_t)((b*32 + c)*8 + h)*512 + f];
  cx[gid] = s;
}

// context[b, h*64+d] = Wa_b[n] + sum_f cx[b,h,f]*Wa[f,n]
__global__ __launch_bounds__(256) void ctx_proj_k(
    const float* __restrict__ cx, const float* __restrict__ Wa,
    const float* __restrict__ Wa_b, float* __restrict__ out) {
  int b = blockIdx.x >> 3, h = blockIdx.x & 7;
  int tid = threadIdx.x;
  __shared__ float cs[512];
  cs[tid]       = cx[(size_t)blockIdx.x*512 + tid];
  cs[tid + 256] = cx[(size_t)blockIdx.x*512 + tid + 256];
  __syncthreads();
  int d = tid & 63, g = tid >> 6;
  float s = 0.f;
  #pragma unroll 8
  for (int f = g*128; f < g*128 + 128; ++f)
    s += cs[f] * Wa[(size_t)f*512 + h*64 + d];
  __shared__ float red[256];
  red[tid] = s;
  __syncthreads();
  if (tid < 64) {
    float tot = red[tid] + red[64+tid] + red[128+tid] + red[192+tid] + Wa_b[h*64 + tid];
    out[b*512 + h*64 + tid] = tot;
  }
}

extern "C" void kernel_launch(void* const* d_in, const int* in_sizes, int n_in,
                              void* d_out, int out_size, void* d_ws, size_t ws_size,
                              hipStream_t stream) {
  (void)in_sizes; (void)n_in; (void)out_size; (void)ws_size;
  const float* lh    = (const float*)d_in[0];
  const float* x     = (const float*)d_in[1];
  const float* Wa_w  = (const float*)d_in[2];
  const float* Wa_b  = (const float*)d_in[3];
  const float* Ua_w  = (const float*)d_in[4];
  const float* Ua_b  = (const float*)d_in[5];
  const float* Wa2_w = (const float*)d_in[6];
  const float* Wa2_b = (const float*)d_in[7];
  const float* Ua2_w = (const float*)d_in[8];
  const float* Ua2_b = (const float*)d_in[9];
  const float* va_w  = (const float*)d_in[10];
  const float* va_b  = (const float*)d_in[11];
  float* out = (float*)d_out;
  char* ws = (char*)d_ws;

  unsigned short* WfT = (unsigned short*)(ws + 0);        // 512 KB
  float* hid    = (float*)(ws + 524288);                  // 64 KB
  float* ubf    = (float*)(ws + 589824);                  // 64 KB
  float* scores = (float*)(ws + 655360);                  // 4 MB
  float* w      = (float*)(ws + 4849664);                 // 4 MB
  float* part   = (float*)(ws + 9043968);                 // 16 MB
  float* cx     = (float*)(ws + 25821184);                // 512 KB (end ~25.1 MB)

  hipLaunchKernelGGL(hid_k, dim3(32), dim3(512), 0, stream, lh, Ua_w, Ua_b, hid);
  hipLaunchKernelGGL(ubf_k, dim3(32), dim3(512), 0, stream,
                     hid, Ua2_w, Ua2_b, Wa_b, Wa2_w, Wa2_b, ubf);
  hipLaunchKernelGGL(wft_k, dim3(512), dim3(256), 0, stream, Wa_w, Wa2_w, WfT);
  hipLaunchKernelGGL(gemm_score_k, dim3(4, 1024), dim3(256), 0, stream,
                     x, WfT, ubf, va_w, va_b, scores);
  hipLaunchKernelGGL(softmax_k, dim3(256), dim3(256), 0, stream, scores, w);
  hipLaunchKernelGGL(mean_k, dim3(512), dim3(256), 0, stream, w, out);
  hipLaunchKernelGGL(ctx_partial_k, dim3(32, 32), dim3(512), 0, stream, x, w, part);
  hipLaunchKernelGGL(ctx_reduce_k, dim3(512), dim3(256), 0, stream, part, cx);
  hipLaunchKernelGGL(ctx_proj_k, dim3(256), dim3(256), 0, stream, cx, Wa_w, Wa_b, out);
}

// Round 2
// 655.280 us; speedup vs baseline: 1.1774x; 1.1774x over previous
//
#include <hip/hip_runtime.h>
#include <hip/hip_bf16.h>

// Problem constants
#define PDIM 4096
#define BDIM 32
#define MDIM (PDIM*BDIM)   // 131072 rows of x
#define KDIM 512           // FEAT
#define NDIM 512           // ATTN
#define NH   8
#define HD   64

typedef __attribute__((ext_vector_type(4))) float f32x4;
typedef __attribute__((ext_vector_type(8))) short bf16x8;

__device__ __forceinline__ unsigned short f2bf(float f) {
  unsigned u = __float_as_uint(f);
  u += 0x7fffu + ((u >> 16) & 1u);
  return (unsigned short)(u >> 16);
}
__device__ __forceinline__ float bf2f(unsigned short u) {
  return __uint_as_float(((unsigned)u) << 16);
}

// fast tanh via exp; abs error ~1e-7, arg clamped so no overflow
__device__ __forceinline__ float fast_tanh(float x) {
  x = fminf(fmaxf(x, -15.f), 15.f);
  float e = __expf(2.f * x);
  return __fdividef(e - 1.f, e + 1.f);
}

// async global->LDS 16B DMA (lane-linear LDS layout, no padding)
#define GLOAD_LDS16(g, l) __builtin_amdgcn_global_load_lds( \
    (const __attribute__((address_space(1))) void*)(g),     \
    (__attribute__((address_space(3))) void*)(l), 16, 0, 0)

// ---------------- x fp32 -> bf16 (one streaming pass) ----------------
__global__ __launch_bounds__(256) void cvt_k(
    const float* __restrict__ x, unsigned short* __restrict__ xbf) {
  size_t i = ((size_t)blockIdx.x * 256 + threadIdx.x) * 8;
  float4 a = *(const float4*)(x + i);
  float4 b = *(const float4*)(x + i + 4);
  ushort4 o0; o0.x = f2bf(a.x); o0.y = f2bf(a.y); o0.z = f2bf(a.z); o0.w = f2bf(a.w);
  ushort4 o1; o1.x = f2bf(b.x); o1.y = f2bf(b.y); o1.z = f2bf(b.z); o1.w = f2bf(b.w);
  *(ushort4*)(xbf + i) = o0;
  *(ushort4*)(xbf + i + 4) = o1;
}

// ---------------- fused hid + ubf (tiny) ----------------
// hid[b,a] = lh[b]@Ua + Ua_b;  ubf[b,n] = hid@Ua2 + Ua2_b + Wa_b@Wa2 + Wa2_b
__global__ __launch_bounds__(512) void hub_k(
    const float* __restrict__ lh, const float* __restrict__ Ua,
    const float* __restrict__ Ua_b, const float* __restrict__ Ua2,
    const float* __restrict__ Ua2_b, const float* __restrict__ Wa_b,
    const float* __restrict__ Wa2, const float* __restrict__ Wa2_b,
    float* __restrict__ ubf) {
  int b = blockIdx.x, tid = threadIdx.x;
  __shared__ float ls[512];
  __shared__ float hs[512];
  ls[tid] = lh[b*512 + tid];
  __syncthreads();
  float s = Ua_b[tid];
  #pragma unroll 8
  for (int k = 0; k < 512; ++k)
    s += ls[k] * Ua[(size_t)k*512 + tid];
  hs[tid] = s;
  __syncthreads();
  int h = tid >> 6, j = tid & 63;
  float u = Ua2_b[j] + Wa2_b[j];
  #pragma unroll 4
  for (int k = 0; k < 64; ++k) {
    u += hs[h*64 + k] * Ua2[k*64 + j];
    u += Wa_b[h*64 + k] * Wa2[k*64 + j];
  }
  ubf[b*512 + tid] = u;
}

// WfT[n,k] = sum_kk Wa[k, h*64+kk] * Wa2[kk, j]   (bf16, N-major = B^T for GEMM)
__global__ __launch_bounds__(256) void wft_k(
    const float* __restrict__ Wa, const float* __restrict__ Wa2,
    unsigned short* __restrict__ WfT) {
  int n = blockIdx.x, tid = threadIdx.x;
  int h = n >> 6, j = n & 63;
  __shared__ float w2[64];
  if (tid < 64) w2[tid] = Wa2[tid*64 + j];
  __syncthreads();
  for (int k = tid; k < 512; k += 256) {
    float s = 0.f;
    #pragma unroll 8
    for (int kk = 0; kk < 64; ++kk)
      s += Wa[(size_t)k*512 + h*64 + kk] * w2[kk];
    WfT[(size_t)n*512 + k] = f2bf(s);
  }
}

// ---------------- main GEMM + score epilogue ----------------
// C[m,n] = xbf[m,:] @ Wf[:,n]; score[m,h] = va_b + sum_j tanh(C+ubf)*va[j]
// LDS layout: 16B chunks indexed [kc][row] (kc = k/8), DMA lane-linear, no pad.
__global__ __launch_bounds__(256, 3) void gemm_score_k(
    const unsigned short* __restrict__ xbf, const unsigned short* __restrict__ WfT,
    const float* __restrict__ ubf, const float* __restrict__ va_w,
    const float* __restrict__ va_b, float* __restrict__ scores) {
  __shared__ __align__(16) unsigned short As[8192];   // 16 KB: 8 kc x 128 rows x 8 bf16
  __shared__ __align__(16) unsigned short Bs[8192];   // 16 KB
  __shared__ float ubf_s[32*128];                     // 16 KB
  int tid = threadIdx.x;
  int bn = blockIdx.x, bm = blockIdx.y;   // bn fast -> A-tile LLC reuse
  int m0 = bm*128, n0 = bn*128;
  #pragma unroll
  for (int t = 0; t < 16; ++t) {
    int idx = t*256 + tid;
    ubf_s[idx] = ubf[(idx >> 7)*512 + n0 + (idx & 127)];
  }
  int lane = tid & 63, w = tid >> 6;
  int quad = lane >> 4, l16 = lane & 15;
  int wr = w >> 1, wc = w & 1;
  f32x4 acc[4][4] = {};

  for (int k0 = 0; k0 < KDIM; k0 += 64) {
    __syncthreads();
    // A: 1024 chunks of 16B; chunk c -> row=c&127, kc=c>>7
    #pragma unroll
    for (int i = 0; i < 4; ++i) {
      int c = i*256 + tid;
      int r = c & 127, kc = c >> 7;
      GLOAD_LDS16(xbf + (size_t)(m0 + r)*512 + k0 + kc*8, As + (size_t)c*8);
    }
    #pragma unroll
    for (int i = 0; i < 4; ++i) {
      int c = i*256 + tid;
      int r = c & 127, kc = c >> 7;
      GLOAD_LDS16(WfT + (size_t)(n0 + r)*512 + k0 + kc*8, Bs + (size_t)c*8);
    }
    __syncthreads();   // compiler drains vmcnt before s_barrier
    #pragma unroll
    for (int kk = 0; kk < 64; kk += 32) {
      int kc = (kk >> 3) + quad;
      bf16x8 af[4], bfr[4];
      #pragma unroll
      for (int ti = 0; ti < 4; ++ti)
        af[ti] = *(const bf16x8*)(As + ((size_t)kc*128 + 64*wr + 16*ti + l16)*8);
      #pragma unroll
      for (int tj = 0; tj < 4; ++tj)
        bfr[tj] = *(const bf16x8*)(Bs + ((size_t)kc*128 + 64*wc + 16*tj + l16)*8);
      #pragma unroll
      for (int ti = 0; ti < 4; ++ti)
        #pragma unroll
        for (int tj = 0; tj < 4; ++tj)
          acc[ti][tj] = __builtin_amdgcn_mfma_f32_16x16x32_bf16(
              af[ti], bfr[tj], acc[ti][tj], 0, 0, 0);
    }
  }

  // epilogue: tanh, dot with va over this head's 64 cols, write score
  int head = bn*2 + wc;
  float va_r[4];
  #pragma unroll
  for (int tj = 0; tj < 4; ++tj) va_r[tj] = va_w[16*tj + l16];
  float vb = va_b[0];
  #pragma unroll
  for (int ti = 0; ti < 4; ++ti) {
    #pragma unroll
    for (int r = 0; r < 4; ++r) {
      int row_loc = 64*wr + 16*ti + 4*quad + r;   // C/D layout: row=quad*4+reg
      int b31 = row_loc & 31;                     // batch index = row % 32
      float s = 0.f;
      #pragma unroll
      for (int tj = 0; tj < 4; ++tj) {
        float xa = acc[ti][tj][r] + ubf_s[b31*128 + 64*wc + 16*tj + l16];
        s += fast_tanh(xa) * va_r[tj];
      }
      s += __shfl_xor(s, 1); s += __shfl_xor(s, 2);
      s += __shfl_xor(s, 4); s += __shfl_xor(s, 8);
      if (l16 == 0) scores[(size_t)(m0 + row_loc)*NH + head] = s + vb;
    }
  }
}

// ---------------- softmax over P per (b,h) ----------------
__global__ __launch_bounds__(256) void softmax_k(
    const float* __restrict__ sc, float* __restrict__ w) {
  int b = blockIdx.x >> 3, h = blockIdx.x & 7;
  int tid = threadIdx.x;
  float v[16];
  float mx = -1e30f;
  #pragma unroll
  for (int i = 0; i < 16; ++i) {
    int p = tid + i*256;
    v[i] = sc[(size_t)(p*32 + b)*NH + h];
    mx = fmaxf(mx, v[i]);
  }
  for (int m = 1; m < 64; m <<= 1) mx = fmaxf(mx, __shfl_xor(mx, m));
  __shared__ float redm[4], reds[4];
  int wid = tid >> 6, lane = tid & 63;
  if (lane == 0) redm[wid] = mx;
  __syncthreads();
  mx = fmaxf(fmaxf(redm[0], redm[1]), fmaxf(redm[2], redm[3]));
  float sum = 0.f;
  #pragma unroll
  for (int i = 0; i < 16; ++i) { v[i] = __expf(v[i] - mx); sum += v[i]; }
  for (int m = 1; m < 64; m <<= 1) sum += __shfl_xor(sum, m);
  if (lane == 0) reds[wid] = sum;
  __syncthreads();
  sum = reds[0] + reds[1] + reds[2] + reds[3];
  float inv = 1.f / sum;
  #pragma unroll
  for (int i = 0; i < 16; ++i) {
    int p = tid + i*256;
    w[(size_t)(p*32 + b)*NH + h] = v[i] * inv;
  }
}

// weight output = mean over heads
__global__ __launch_bounds__(256) void mean_k(
    const float* __restrict__ w, float* __restrict__ out) {
  int m = blockIdx.x*256 + threadIdx.x;
  const float4* p = (const float4*)(w + (size_t)m*NH);
  float4 a = p[0], c = p[1];
  out[BDIM*NDIM + m] = (a.x+a.y+a.z+a.w + c.x+c.y+c.z+c.w) * 0.125f;
}

// ---------------- context: cx[b,h,f] = sum_p w[p,b,h]*x[p,b,f] ----------------
// bf16 x, per-wave accumulate 64 p-rows, LDS cross-wave reduce.
__global__ __launch_bounds__(256) void ctx_partial_k(
    const unsigned short* __restrict__ xbf, const float* __restrict__ w,
    float* __restrict__ part) {
  int pc = blockIdx.x;   // 16 chunks of 256 pixels
  int b  = blockIdx.y;   // 32 batches
  int tid = threadIdx.x;
  __shared__ float wl[256*8];
  __shared__ float red[4][512];
  {
    const float4* wp = (const float4*)(w + ((size_t)((pc*256 + tid)*32 + b))*NH);
    float4 a = wp[0], c = wp[1];
    float4* dst = (float4*)(wl + tid*8);
    dst[0] = a; dst[1] = c;
  }
  __syncthreads();
  int lane = tid & 63, wv = tid >> 6;
  float acc[8][8];
  #pragma unroll
  for (int h = 0; h < 8; ++h)
    #pragma unroll
    for (int j = 0; j < 8; ++j) acc[h][j] = 0.f;
  for (int i = 0; i < 64; ++i) {
    int pl = wv*64 + i;
    bf16x8 xv = *(const bf16x8*)(xbf + ((size_t)((pc*256 + pl)*32 + b))*512 + lane*8);
    float xf[8];
    #pragma unroll
    for (int j = 0; j < 8; ++j) xf[j] = bf2f((unsigned short)xv[j]);
    #pragma unroll
    for (int h = 0; h < 8; ++h) {
      float ww = wl[pl*8 + h];
      #pragma unroll
      for (int j = 0; j < 8; ++j) acc[h][j] += ww * xf[j];
    }
  }
  // cross-wave reduce per head, write part[b][pc][h][f]
  for (int h = 0; h < 8; ++h) {
    #pragma unroll
    for (int j = 0; j < 8; j += 4)
      *(float4*)(&red[wv][lane*8 + j]) = *(float4*)(&acc[h][j]);
    __syncthreads();
    if (tid < 64) {
      #pragma unroll
      for (int j = 0; j < 8; ++j) {
        int f = tid*8 + j;
        part[((size_t)(b*16 + pc)*NH + h)*512 + f] =
            red[0][f] + red[1][f] + red[2][f] + red[3][f];
      }
    }
    __syncthreads();
  }
}

__global__ __launch_bounds__(256) void ctx_reduce_k(
    const float* __restrict__ part, float* __restrict__ cx) {
  int gid = blockIdx.x*256 + threadIdx.x;  // (b*8+h)*512+f
  int f = gid & 511;
  int bh = gid >> 9;
  int h = bh & 7, b = bh >> 3;
  float s = 0.f;
  #pragma unroll
  for (int pc = 0; pc < 16; ++pc)
    s += part[((size_t)(b*16 + pc)*NH + h)*512 + f];
  cx[gid] = s;
}

// context[b, h*64+d] = Wa_b[n] + sum_f cx[b,h,f]*Wa[f,n]
__global__ __launch_bounds__(256) void ctx_proj_k(
    const float* __restrict__ cx, const float* __restrict__ Wa,
    const float* __restrict__ Wa_b, float* __restrict__ out) {
  int b = blockIdx.x >> 3, h = blockIdx.x & 7;
  int tid = threadIdx.x;
  __shared__ float cs[512];
  cs[tid]       = cx[(size_t)blockIdx.x*512 + tid];
  cs[tid + 256] = cx[(size_t)blockIdx.x*512 + tid + 256];
  __syncthreads();
  int d = tid & 63, g = tid >> 6;
  float s = 0.f;
  #pragma unroll 8
  for (int f = g*128; f < g*128 + 128; ++f)
    s += cs[f] * Wa[(size_t)f*512 + h*64 + d];
  __shared__ float red[256];
  red[tid] = s;
  __syncthreads();
  if (tid < 64) {
    float tot = red[tid] + red[64+tid] + red[128+tid] + red[192+tid] + Wa_b[h*64 + tid];
    out[b*512 + h*64 + tid] = tot;
  }
}

extern "C" void kernel_launch(void* const* d_in, const int* in_sizes, int n_in,
                              void* d_out, int out_size, void* d_ws, size_t ws_size,
                              hipStream_t stream) {
  (void)in_sizes; (void)n_in; (void)out_size; (void)ws_size;
  const float* lh    = (const float*)d_in[0];
  const float* x     = (const float*)d_in[1];
  const float* Wa_w  = (const float*)d_in[2];
  const float* Wa_b  = (const float*)d_in[3];
  const float* Ua_w  = (const float*)d_in[4];
  const float* Ua_b  = (const float*)d_in[5];
  const float* Wa2_w = (const float*)d_in[6];
  const float* Wa2_b = (const float*)d_in[7];
  const float* Ua2_w = (const float*)d_in[8];
  const float* Ua2_b = (const float*)d_in[9];
  const float* va_w  = (const float*)d_in[10];
  const float* va_b  = (const float*)d_in[11];
  float* out = (float*)d_out;
  char* ws = (char*)d_ws;

  unsigned short* xbf = (unsigned short*)(ws);            // 134,217,728 B
  unsigned short* WfT = (unsigned short*)(ws + 134217728);// 524,288 B
  float* ubf    = (float*)(ws + 134742016);               // 65,536 B
  float* scores = (float*)(ws + 134807552);               // 4,194,304 B
  float* w      = (float*)(ws + 139001856);               // 4,194,304 B
  float* part   = (float*)(ws + 143196160);               // 8,388,608 B
  float* cx     = (float*)(ws + 151584768);               // 65,536 B  (end ~151.65 MB)

  hipLaunchKernelGGL(cvt_k, dim3(32768), dim3(256), 0, stream, x, xbf);
  hipLaunchKernelGGL(hub_k, dim3(32), dim3(512), 0, stream,
                     lh, Ua_w, Ua_b, Ua2_w, Ua2_b, Wa_b, Wa2_w, Wa2_b, ubf);
  hipLaunchKernelGGL(wft_k, dim3(512), dim3(256), 0, stream, Wa_w, Wa2_w, WfT);
  hipLaunchKernelGGL(gemm_score_k, dim3(4, 1024), dim3(256), 0, stream,
                     xbf, WfT, ubf, va_w, va_b, scores);
  hipLaunchKernelGGL(softmax_k, dim3(256), dim3(256), 0, stream, scores, w);
  hipLaunchKernelGGL(mean_k, dim3(512), dim3(256), 0, stream, w, out);
  hipLaunchKernelGGL(ctx_partial_k, dim3(16, 32), dim3(256), 0, stream, xbf, w, part);
  hipLaunchKernelGGL(ctx_reduce_k, dim3(512), dim3(256), 0, stream, part, cx);
  hipLaunchKernelGGL(ctx_proj_k, dim3(256), dim3(256), 0, stream, cx, Wa_w, Wa_b, out);
}